// Round 1
// baseline (570.305 us; speedup 1.0000x reference)
//
#include <hip/hip_runtime.h>
#include <math.h>

#define BB 4
#define TT 1024
#define DD 512
#define HH 8
#define DHH 64

__device__ __forceinline__ float softplus_f(float z) {
    return fmaxf(z, 0.f) + log1pf(__expf(-fabsf(z)));
}

// ---------------------------------------------------------------------------
// K1: fused projection GEMM: x[4096,512] @ [Wq|Wk|Wv|Ws][512,1544]
// q,k,v stored [B,H,T,DH] in workspace; sigma -> d_out (softplus + 1e-6)
// ---------------------------------------------------------------------------
__global__ __launch_bounds__(256) void proj_kernel(
    const float* __restrict__ x,
    const float* __restrict__ Wq, const float* __restrict__ bq,
    const float* __restrict__ Wk, const float* __restrict__ bk,
    const float* __restrict__ Wv, const float* __restrict__ bv,
    const float* __restrict__ Ws, const float* __restrict__ bs,
    float* __restrict__ qws, float* __restrict__ kws, float* __restrict__ vws,
    float* __restrict__ sigma_out)
{
    __shared__ float xs[16][68];
    __shared__ float wsd[16][68];
    const int tid = threadIdx.x;
    const int ct  = blockIdx.x;        // 0..24 (col tile of 64)
    const int m0  = blockIdx.y * 64;   // row tile

    const float* W; const float* bias; int nc, cl0, seg;
    if (ct < 8)       { W = Wq; bias = bq; nc = 512; cl0 = ct*64;      seg = 0; }
    else if (ct < 16) { W = Wk; bias = bk; nc = 512; cl0 = (ct-8)*64;  seg = 1; }
    else if (ct < 24) { W = Wv; bias = bv; nc = 512; cl0 = (ct-16)*64; seg = 2; }
    else              { W = Ws; bias = bs; nc = 8;   cl0 = 0;          seg = 3; }

    const int ty  = tid >> 4, tx  = tid & 15;
    const int lm  = tid >> 2, lkq = tid & 3;
    const int lkk = tid >> 4, lcq = tid & 15;

    float acc[4][4];
    #pragma unroll
    for (int i = 0; i < 4; ++i)
        #pragma unroll
        for (int j = 0; j < 4; ++j) acc[i][j] = 0.f;

    for (int k0 = 0; k0 < 512; k0 += 16) {
        float4 xv = *(const float4*)&x[(m0 + lm) * 512 + k0 + lkq * 4];
        float4 wv = make_float4(0.f, 0.f, 0.f, 0.f);
        int col = cl0 + lcq * 4;
        if (col + 4 <= nc) wv = *(const float4*)&W[(k0 + lkk) * nc + col];
        __syncthreads();
        xs[lkq*4+0][lm] = xv.x;
        xs[lkq*4+1][lm] = xv.y;
        xs[lkq*4+2][lm] = xv.z;
        xs[lkq*4+3][lm] = xv.w;
        *(float4*)&wsd[lkk][lcq*4] = wv;
        __syncthreads();
        #pragma unroll
        for (int kk = 0; kk < 16; ++kk) {
            float4 a = *(float4*)&xs[kk][ty*4];
            float4 b = *(float4*)&wsd[kk][tx*4];
            float av[4] = {a.x, a.y, a.z, a.w};
            float bv4[4] = {b.x, b.y, b.z, b.w};
            #pragma unroll
            for (int i = 0; i < 4; ++i)
                #pragma unroll
                for (int j = 0; j < 4; ++j)
                    acc[i][j] += av[i] * bv4[j];
        }
    }

    #pragma unroll
    for (int i = 0; i < 4; ++i) {
        int r = m0 + ty*4 + i;
        int b = r >> 10, t = r & 1023;
        #pragma unroll
        for (int j = 0; j < 4; ++j) {
            float vv = acc[i][j];
            if (seg < 3) {
                int cl = cl0 + tx*4 + j;       // 0..511 within segment
                vv += bias[cl];
                int h = cl >> 6, dh = cl & 63;
                float* dst = (seg == 0) ? qws : (seg == 1) ? kws : vws;
                dst[(size_t)((b*HH + h)*TT + t) * 64 + dh] = vv;
            } else {
                int hh = tx*4 + j;
                if (hh < 8) {
                    float z = vv + bias[hh];
                    sigma_out[(size_t)(b*HH + hh)*TT + t] = softplus_f(z) + 1e-6f;
                }
            }
        }
    }
}

// ---------------------------------------------------------------------------
// K2: series = softmax(Q K^T / 8). Block: one (b,h), 16 q-rows. Wave owns 4
// rows; full 1024-wide logit row held in registers (4 x 16 per lane).
// ---------------------------------------------------------------------------
__global__ __launch_bounds__(256) void series_kernel(
    const float* __restrict__ q, const float* __restrict__ k,
    float* __restrict__ series)
{
    __shared__ float q_lds[16][68];
    __shared__ float k_lds[64][68];
    const int tid = threadIdx.x;
    const int bh  = blockIdx.y;        // 0..31
    const int r0  = blockIdx.x * 16;   // q-row tile
    const int w   = tid >> 6, tc = tid & 63;

    {
        int row = tid >> 4, dq = tid & 15;
        float4 qv = *(const float4*)&q[(size_t)(bh*TT + r0 + row) * 64 + dq*4];
        q_lds[row][dq*4+0] = qv.x * 0.125f;   // fold 1/sqrt(64)
        q_lds[row][dq*4+1] = qv.y * 0.125f;
        q_lds[row][dq*4+2] = qv.z * 0.125f;
        q_lds[row][dq*4+3] = qv.w * 0.125f;
    }

    float lg[4][16];
    #pragma unroll
    for (int i = 0; i < 4; ++i)
        #pragma unroll
        for (int j = 0; j < 16; ++j) lg[i][j] = 0.f;

    #pragma unroll
    for (int st = 0; st < 16; ++st) {
        __syncthreads();
        #pragma unroll
        for (int l = 0; l < 4; ++l) {
            int idx = tid + l*256;
            int s = idx >> 4, dq = idx & 15;
            *(float4*)&k_lds[s][dq*4] =
                *(const float4*)&k[(size_t)(bh*TT + st*64 + s) * 64 + dq*4];
        }
        __syncthreads();
        #pragma unroll
        for (int dh0 = 0; dh0 < 64; dh0 += 4) {
            float4 kv = *(float4*)&k_lds[tc][dh0];
            #pragma unroll
            for (int i = 0; i < 4; ++i) {
                float4 qv = *(float4*)&q_lds[w*4 + i][dh0];
                lg[i][st] += qv.x*kv.x + qv.y*kv.y + qv.z*kv.z + qv.w*kv.w;
            }
        }
    }

    #pragma unroll
    for (int i = 0; i < 4; ++i) {
        float e[16]; float sum = 0.f;
        #pragma unroll
        for (int j = 0; j < 16; ++j) { e[j] = __expf(lg[i][j]); sum += e[j]; }
        sum += __shfl_xor(sum, 32);
        sum += __shfl_xor(sum, 16);
        sum += __shfl_xor(sum, 8);
        sum += __shfl_xor(sum, 4);
        sum += __shfl_xor(sum, 2);
        sum += __shfl_xor(sum, 1);
        float inv = 1.f / sum;
        float* srow = series + (size_t)(bh*TT + r0 + w*4 + i) * 1024;
        #pragma unroll
        for (int j = 0; j < 16; ++j) srow[j*64 + tc] = e[j] * inv;
    }
}

// ---------------------------------------------------------------------------
// K3: out_h = series @ V  (per (b,h): [1024,1024] @ [1024,64])
// Block: one (b,h), 64 rows. Wave owns 16 rows, lane = dh.
// ---------------------------------------------------------------------------
__global__ __launch_bounds__(256) void pv_kernel(
    const float* __restrict__ series, const float* __restrict__ v,
    float* __restrict__ out_h)
{
    __shared__ float p_lds[64][68];
    __shared__ float v_lds[64][68];
    const int tid = threadIdx.x;
    const int bh  = blockIdx.y;
    const int r0  = blockIdx.x * 64;
    const int w   = tid >> 6, dh = tid & 63;

    float acc[16];
    #pragma unroll
    for (int i = 0; i < 16; ++i) acc[i] = 0.f;

    for (int st = 0; st < 16; ++st) {
        __syncthreads();
        #pragma unroll
        for (int l = 0; l < 4; ++l) {
            int idx = tid + l*256;
            int rr = idx >> 4, sq = idx & 15;
            *(float4*)&p_lds[rr][sq*4] =
                *(const float4*)&series[(size_t)(bh*TT + r0 + rr)*1024 + st*64 + sq*4];
            *(float4*)&v_lds[rr][sq*4] =
                *(const float4*)&v[(size_t)(bh*TT + st*64 + rr)*64 + sq*4];
        }
        __syncthreads();
        #pragma unroll
        for (int s4 = 0; s4 < 16; ++s4) {
            float vv0 = v_lds[s4*4+0][dh];
            float vv1 = v_lds[s4*4+1][dh];
            float vv2 = v_lds[s4*4+2][dh];
            float vv3 = v_lds[s4*4+3][dh];
            #pragma unroll
            for (int i = 0; i < 16; ++i) {
                float4 p4 = *(float4*)&p_lds[w*16 + i][s4*4];
                acc[i] += p4.x*vv0 + p4.y*vv1 + p4.z*vv2 + p4.w*vv3;
            }
        }
    }
    #pragma unroll
    for (int i = 0; i < 16; ++i)
        out_h[(size_t)(bh*TT + r0 + w*16 + i)*64 + dh] = acc[i];
}

// ---------------------------------------------------------------------------
// K4: out = out_h(reordered) @ Wo + bo
// ---------------------------------------------------------------------------
__global__ __launch_bounds__(256) void outproj_kernel(
    const float* __restrict__ oh, const float* __restrict__ Wo,
    const float* __restrict__ bo, float* __restrict__ out)
{
    __shared__ float xs[16][68];
    __shared__ float wsd[16][68];
    const int tid = threadIdx.x;
    const int c0  = blockIdx.x * 64;
    const int m0  = blockIdx.y * 64;
    const int ty  = tid >> 4, tx  = tid & 15;
    const int lm  = tid >> 2, lkq = tid & 3;
    const int lkk = tid >> 4, lcq = tid & 15;

    float acc[4][4];
    #pragma unroll
    for (int i = 0; i < 4; ++i)
        #pragma unroll
        for (int j = 0; j < 4; ++j) acc[i][j] = 0.f;

    for (int k0 = 0; k0 < 512; k0 += 16) {
        int r = m0 + lm; int b = r >> 10, t = r & 1023;
        int ck = k0 + lkq*4; int h = ck >> 6, dhh = ck & 63;
        float4 xv = *(const float4*)&oh[(size_t)((b*HH + h)*TT + t)*64 + dhh];
        float4 wv = *(const float4*)&Wo[(size_t)(k0 + lkk)*512 + c0 + lcq*4];
        __syncthreads();
        xs[lkq*4+0][lm] = xv.x;
        xs[lkq*4+1][lm] = xv.y;
        xs[lkq*4+2][lm] = xv.z;
        xs[lkq*4+3][lm] = xv.w;
        *(float4*)&wsd[lkk][lcq*4] = wv;
        __syncthreads();
        #pragma unroll
        for (int kk = 0; kk < 16; ++kk) {
            float4 a = *(float4*)&xs[kk][ty*4];
            float4 b4 = *(float4*)&wsd[kk][tx*4];
            float av[4] = {a.x, a.y, a.z, a.w};
            float bv4[4] = {b4.x, b4.y, b4.z, b4.w};
            #pragma unroll
            for (int i = 0; i < 4; ++i)
                #pragma unroll
                for (int j = 0; j < 4; ++j)
                    acc[i][j] += av[i] * bv4[j];
        }
    }

    #pragma unroll
    for (int i = 0; i < 4; ++i)
        #pragma unroll
        for (int j = 0; j < 4; ++j)
            out[(size_t)(m0 + ty*4 + i)*512 + c0 + tx*4 + j] =
                acc[i][j] + bo[c0 + tx*4 + j];
}

// ---------------------------------------------------------------------------
// K5: prior. One wave per (b,h,t) row: exp(-(t-s)^2/(2*s2)), normalize.
// ---------------------------------------------------------------------------
__global__ __launch_bounds__(256) void prior_kernel(
    const float* __restrict__ sigma, float* __restrict__ prior)
{
    const int tid = threadIdx.x;
    const int w = tid >> 6, tc = tid & 63;
    const int row = blockIdx.x * 4 + w;      // 0..32767
    const int t = row & 1023;

    float sg = sigma[row];
    float c = 1.f / (2.f * (sg*sg + 1e-6f));

    float e[16]; float sum = 0.f;
    #pragma unroll
    for (int j = 0; j < 16; ++j) {
        int s = j*64 + tc;
        float d = (float)(t - s);
        e[j] = __expf(-(d*d) * c);
        sum += e[j];
    }
    sum += __shfl_xor(sum, 32);
    sum += __shfl_xor(sum, 16);
    sum += __shfl_xor(sum, 8);
    sum += __shfl_xor(sum, 4);
    sum += __shfl_xor(sum, 2);
    sum += __shfl_xor(sum, 1);
    float inv = 1.f / (sum + 1e-9f);

    float* pr = prior + (size_t)row * 1024;
    #pragma unroll
    for (int j = 0; j < 16; ++j) pr[j*64 + tc] = e[j] * inv;
}

// ---------------------------------------------------------------------------
extern "C" void kernel_launch(void* const* d_in, const int* in_sizes, int n_in,
                              void* d_out, int out_size, void* d_ws, size_t ws_size,
                              hipStream_t stream)
{
    const float* x    = (const float*)d_in[0];
    const float* Wq_w = (const float*)d_in[1];
    const float* Wq_b = (const float*)d_in[2];
    const float* Wk_w = (const float*)d_in[3];
    const float* Wk_b = (const float*)d_in[4];
    const float* Wv_w = (const float*)d_in[5];
    const float* Wv_b = (const float*)d_in[6];
    const float* Ws_w = (const float*)d_in[7];
    const float* Ws_b = (const float*)d_in[8];
    const float* Wo_w = (const float*)d_in[9];
    const float* Wo_b = (const float*)d_in[10];

    float* out    = (float*)d_out;                      // [B,T,D]     2,097,152
    float* series = out + (size_t)BB*TT*DD;             // [B,H,T,T]  33,554,432
    float* prior  = series + (size_t)BB*HH*TT*TT;       // [B,H,T,T]  33,554,432
    float* sigma  = prior + (size_t)BB*HH*TT*TT;        // [B,H,T]        32,768

    float* qws = (float*)d_ws;                          // [B,H,T,DH]
    float* kws = qws + (size_t)BB*HH*TT*DHH;
    float* vws = kws + (size_t)BB*HH*TT*DHH;
    float* oh  = vws + (size_t)BB*HH*TT*DHH;            // [B,H,T,DH]

    proj_kernel<<<dim3(25, 64), 256, 0, stream>>>(
        x, Wq_w, Wq_b, Wk_w, Wk_b, Wv_w, Wv_b, Ws_w, Ws_b,
        qws, kws, vws, sigma);

    series_kernel<<<dim3(64, 32), 256, 0, stream>>>(qws, kws, series);

    pv_kernel<<<dim3(16, 32), 256, 0, stream>>>(series, vws, oh);

    outproj_kernel<<<dim3(8, 64), 256, 0, stream>>>(oh, Wo_w, Wo_b, out);

    prior_kernel<<<8192, 256, 0, stream>>>(sigma, prior);
}

// Round 2
// 234.244 us; speedup vs baseline: 2.4347x; 2.4347x over previous
//
#include <hip/hip_runtime.h>
#include <math.h>

#define BB 4
#define TT 1024
#define DD 512
#define HH 8
#define DHH 64

typedef short bf8_t __attribute__((ext_vector_type(8)));
typedef float f32x4 __attribute__((ext_vector_type(4)));

__device__ __forceinline__ float softplus_f(float z) {
    return fmaxf(z, 0.f) + log1pf(__expf(-fabsf(z)));
}

__device__ __forceinline__ unsigned short f2bf(float f) {
    union { float f; unsigned int u; } v; v.f = f;
    return (unsigned short)((v.u + 0x7FFFu + ((v.u >> 16) & 1u)) >> 16);
}

// ---------------------------------------------------------------------------
// K1: fused projection GEMM: x[4096,512] @ [Wq|Wk|Wv|Ws][512,1544]
// q (pre-scaled by 0.125), k, v stored bf16 [B,H,T,64]; sigma -> d_out
// ---------------------------------------------------------------------------
__global__ __launch_bounds__(256) void proj_kernel(
    const float* __restrict__ x,
    const float* __restrict__ Wq, const float* __restrict__ bq,
    const float* __restrict__ Wk, const float* __restrict__ bk,
    const float* __restrict__ Wv, const float* __restrict__ bv,
    const float* __restrict__ Ws, const float* __restrict__ bs,
    unsigned short* __restrict__ qbf, unsigned short* __restrict__ kbf,
    unsigned short* __restrict__ vbf, float* __restrict__ sigma_out)
{
    __shared__ float xs[16][68];
    __shared__ float wsd[16][68];
    const int tid = threadIdx.x;
    const int ct  = blockIdx.x;        // 0..24 (col tile of 64)
    const int m0  = blockIdx.y * 64;   // row tile

    const float* W; const float* bias; int nc, cl0, seg;
    if (ct < 8)       { W = Wq; bias = bq; nc = 512; cl0 = ct*64;      seg = 0; }
    else if (ct < 16) { W = Wk; bias = bk; nc = 512; cl0 = (ct-8)*64;  seg = 1; }
    else if (ct < 24) { W = Wv; bias = bv; nc = 512; cl0 = (ct-16)*64; seg = 2; }
    else              { W = Ws; bias = bs; nc = 8;   cl0 = 0;          seg = 3; }

    const int ty  = tid >> 4, tx  = tid & 15;
    const int lm  = tid >> 2, lkq = tid & 3;
    const int lkk = tid >> 4, lcq = tid & 15;

    float acc[4][4];
    #pragma unroll
    for (int i = 0; i < 4; ++i)
        #pragma unroll
        for (int j = 0; j < 4; ++j) acc[i][j] = 0.f;

    for (int k0 = 0; k0 < 512; k0 += 16) {
        float4 xv = *(const float4*)&x[(m0 + lm) * 512 + k0 + lkq * 4];
        float4 wv = make_float4(0.f, 0.f, 0.f, 0.f);
        int col = cl0 + lcq * 4;
        if (col + 4 <= nc) wv = *(const float4*)&W[(k0 + lkk) * nc + col];
        __syncthreads();
        xs[lkq*4+0][lm] = xv.x;
        xs[lkq*4+1][lm] = xv.y;
        xs[lkq*4+2][lm] = xv.z;
        xs[lkq*4+3][lm] = xv.w;
        *(float4*)&wsd[lkk][lcq*4] = wv;
        __syncthreads();
        #pragma unroll
        for (int kk = 0; kk < 16; ++kk) {
            float4 a = *(float4*)&xs[kk][ty*4];
            float4 b = *(float4*)&wsd[kk][tx*4];
            float av[4] = {a.x, a.y, a.z, a.w};
            float bv4[4] = {b.x, b.y, b.z, b.w};
            #pragma unroll
            for (int i = 0; i < 4; ++i)
                #pragma unroll
                for (int j = 0; j < 4; ++j)
                    acc[i][j] += av[i] * bv4[j];
        }
    }

    #pragma unroll
    for (int i = 0; i < 4; ++i) {
        int r = m0 + ty*4 + i;
        int b = r >> 10, t = r & 1023;
        if (seg < 3) {
            const float scale = (seg == 0) ? 0.125f : 1.0f;
            int h = cl0 >> 6;
            ushort4 pk;
            pk.x = f2bf((acc[i][0] + bias[cl0 + tx*4 + 0]) * scale);
            pk.y = f2bf((acc[i][1] + bias[cl0 + tx*4 + 1]) * scale);
            pk.z = f2bf((acc[i][2] + bias[cl0 + tx*4 + 2]) * scale);
            pk.w = f2bf((acc[i][3] + bias[cl0 + tx*4 + 3]) * scale);
            unsigned short* dst = (seg == 0) ? qbf : (seg == 1) ? kbf : vbf;
            *(ushort4*)&dst[((size_t)((b*HH + h)*TT + t))*64 + tx*4] = pk;
        } else {
            #pragma unroll
            for (int j = 0; j < 4; ++j) {
                int hh = tx*4 + j;
                if (hh < 8) {
                    float z = acc[i][j] + bias[hh];
                    sigma_out[(size_t)(b*HH + hh)*TT + t] = softplus_f(z) + 1e-6f;
                }
            }
        }
    }
}

// ---------------------------------------------------------------------------
// K2: fused attention: series = softmax(QK^T/8) (written), oh = series @ V.
// Block: one (b,h) x 64 q-rows; 4 waves x 16 rows. bf16 MFMA 16x16x32.
// Sweep1: row sums of exp(S). Sweep2: recompute S, write normalized series,
// PV via MFMA with V staged transposed+swizzled in LDS; scale O by 1/sum.
// ---------------------------------------------------------------------------
__global__ __launch_bounds__(256) void attn_kernel(
    const unsigned short* __restrict__ qbf,
    const unsigned short* __restrict__ kbf,
    const unsigned short* __restrict__ vbf,
    float* __restrict__ series, float* __restrict__ oh)
{
    __shared__ unsigned short k_lds[64][72];   // K chunk, row-major [s][dh]
    __shared__ unsigned short v_lds[64][64];   // V^T chunk [dh][s], 16B-granule swizzled
    __shared__ unsigned short p_lds[4][16][72];// per-wave P tile [qrow][s]

    const int tid = threadIdx.x;
    const int w  = tid >> 6, l = tid & 63;
    const int lr = l & 15,  lg = l >> 4;
    const int bh = blockIdx.y;
    const int qr = blockIdx.x * 64 + w * 16;   // wave's first q row

    // Q fragments, resident all kernel (A operand: row = lr, k = lg*8 + j)
    bf8_t aq[2];
    {
        const unsigned short* qrow = &qbf[((size_t)bh * TT + qr + lr) * 64];
        aq[0] = *(const bf8_t*)&qrow[lg * 8];
        aq[1] = *(const bf8_t*)&qrow[32 + lg * 8];
    }

    // ---------------- sweep 1: row sums ----------------
    float psum[4] = {0.f, 0.f, 0.f, 0.f};
    for (int st = 0; st < 16; ++st) {
        __syncthreads();
        #pragma unroll
        for (int rep = 0; rep < 2; ++rep) {
            int idx = rep * 256 + tid;
            int tr = idx >> 3, cg = idx & 7;
            *(int4*)&k_lds[tr][cg * 8] =
                *(const int4*)&kbf[((size_t)bh * TT + st * 64 + tr) * 64 + cg * 8];
        }
        __syncthreads();
        #pragma unroll
        for (int nb = 0; nb < 4; ++nb) {
            f32x4 acc = {0.f, 0.f, 0.f, 0.f};
            #pragma unroll
            for (int c = 0; c < 2; ++c) {
                bf8_t bk = *(const bf8_t*)&k_lds[nb * 16 + lr][c * 32 + lg * 8];
                acc = __builtin_amdgcn_mfma_f32_16x16x32_bf16(aq[c], bk, acc, 0, 0, 0);
            }
            #pragma unroll
            for (int r = 0; r < 4; ++r) psum[r] += __expf(acc[r]);
        }
    }
    #pragma unroll
    for (int r = 0; r < 4; ++r) {
        psum[r] += __shfl_xor(psum[r], 1);
        psum[r] += __shfl_xor(psum[r], 2);
        psum[r] += __shfl_xor(psum[r], 4);
        psum[r] += __shfl_xor(psum[r], 8);
    }
    float inv[4];
    #pragma unroll
    for (int r = 0; r < 4; ++r) inv[r] = 1.f / psum[r];

    // ---------------- sweep 2: series + PV ----------------
    f32x4 oacc[4];
    #pragma unroll
    for (int nb = 0; nb < 4; ++nb) oacc[nb] = (f32x4){0.f, 0.f, 0.f, 0.f};

    for (int st = 0; st < 16; ++st) {
        __syncthreads();
        #pragma unroll
        for (int rep = 0; rep < 2; ++rep) {
            int idx = rep * 256 + tid;
            int tr = idx >> 3, cg = idx & 7;
            *(int4*)&k_lds[tr][cg * 8] =
                *(const int4*)&kbf[((size_t)bh * TT + st * 64 + tr) * 64 + cg * 8];
        }
        // V: load [s][dh] coalesced, scatter-write transposed+swizzled [dh][s]
        #pragma unroll
        for (int rep = 0; rep < 2; ++rep) {
            int idx = rep * 256 + tid;
            int sr = idx >> 3, cg = idx & 7;
            int4 vv = *(const int4*)&vbf[((size_t)bh * TT + st * 64 + sr) * 64 + cg * 8];
            const unsigned short* pv = (const unsigned short*)&vv;
            #pragma unroll
            for (int j = 0; j < 8; ++j) {
                int row = cg * 8 + j;                        // dh
                int gsw = ((sr >> 3) ^ j ^ cg) & 7;          // g ^ (row&7) ^ (row>>3)
                v_lds[row][gsw * 8 + (sr & 7)] = pv[j];
            }
        }
        __syncthreads();

        // recompute S block, write normalized series, stash unnormalized e
        #pragma unroll
        for (int nb = 0; nb < 4; ++nb) {
            f32x4 acc = {0.f, 0.f, 0.f, 0.f};
            #pragma unroll
            for (int c = 0; c < 2; ++c) {
                bf8_t bk = *(const bf8_t*)&k_lds[nb * 16 + lr][c * 32 + lg * 8];
                acc = __builtin_amdgcn_mfma_f32_16x16x32_bf16(aq[c], bk, acc, 0, 0, 0);
            }
            #pragma unroll
            for (int r = 0; r < 4; ++r) {
                float e = __expf(acc[r]);
                series[((size_t)bh * TT + qr + lg * 4 + r) * TT + st * 64 + nb * 16 + lr]
                    = e * inv[r];
                p_lds[w][lg * 4 + r][nb * 16 + lr] = f2bf(e);
            }
        }

        // PV: A = P (row = lr, k = lg*8+j), B = V^T frag from swizzled LDS
        bf8_t pa0 = *(const bf8_t*)&p_lds[w][lr][lg * 8];
        bf8_t pa1 = *(const bf8_t*)&p_lds[w][lr][32 + lg * 8];
        #pragma unroll
        for (int nb = 0; nb < 4; ++nb) {
            #pragma unroll
            for (int c = 0; c < 2; ++c) {
                int row = nb * 16 + lr;
                int gsw = ((c * 4 + lg) ^ (row & 7) ^ (row >> 3)) & 7;
                bf8_t bv = *(const bf8_t*)&v_lds[row][gsw * 8];
                oacc[nb] = __builtin_amdgcn_mfma_f32_16x16x32_bf16(
                    (c == 0) ? pa0 : pa1, bv, oacc[nb], 0, 0, 0);
            }
        }
    }

    #pragma unroll
    for (int nb = 0; nb < 4; ++nb)
        #pragma unroll
        for (int r = 0; r < 4; ++r)
            oh[((size_t)bh * TT + qr + lg * 4 + r) * 64 + nb * 16 + lr]
                = oacc[nb][r] * inv[r];
}

// ---------------------------------------------------------------------------
// K4: out = out_h(reordered) @ Wo + bo
// ---------------------------------------------------------------------------
__global__ __launch_bounds__(256) void outproj_kernel(
    const float* __restrict__ ohp, const float* __restrict__ Wo,
    const float* __restrict__ bo, float* __restrict__ out)
{
    __shared__ float xs[16][68];
    __shared__ float wsd[16][68];
    const int tid = threadIdx.x;
    const int c0  = blockIdx.x * 64;
    const int m0  = blockIdx.y * 64;
    const int ty  = tid >> 4, tx  = tid & 15;
    const int lm  = tid >> 2, lkq = tid & 3;
    const int lkk = tid >> 4, lcq = tid & 15;

    float acc[4][4];
    #pragma unroll
    for (int i = 0; i < 4; ++i)
        #pragma unroll
        for (int j = 0; j < 4; ++j) acc[i][j] = 0.f;

    for (int k0 = 0; k0 < 512; k0 += 16) {
        int r = m0 + lm; int b = r >> 10, t = r & 1023;
        int ck = k0 + lkq*4; int h = ck >> 6, dhh = ck & 63;
        float4 xv = *(const float4*)&ohp[(size_t)((b*HH + h)*TT + t)*64 + dhh];
        float4 wv = *(const float4*)&Wo[(size_t)(k0 + lkk)*512 + c0 + lcq*4];
        __syncthreads();
        xs[lkq*4+0][lm] = xv.x;
        xs[lkq*4+1][lm] = xv.y;
        xs[lkq*4+2][lm] = xv.z;
        xs[lkq*4+3][lm] = xv.w;
        *(float4*)&wsd[lkk][lcq*4] = wv;
        __syncthreads();
        #pragma unroll
        for (int kk = 0; kk < 16; ++kk) {
            float4 a = *(float4*)&xs[kk][ty*4];
            float4 b4 = *(float4*)&wsd[kk][tx*4];
            float av[4] = {a.x, a.y, a.z, a.w};
            float bv4[4] = {b4.x, b4.y, b4.z, b4.w};
            #pragma unroll
            for (int i = 0; i < 4; ++i)
                #pragma unroll
                for (int j = 0; j < 4; ++j)
                    acc[i][j] += av[i] * bv4[j];
        }
    }

    #pragma unroll
    for (int i = 0; i < 4; ++i)
        #pragma unroll
        for (int j = 0; j < 4; ++j)
            out[(size_t)(m0 + ty*4 + i)*512 + c0 + tx*4 + j] =
                acc[i][j] + bo[c0 + tx*4 + j];
}

// ---------------------------------------------------------------------------
// K5: prior. One wave per (b,h,t) row.
// ---------------------------------------------------------------------------
__global__ __launch_bounds__(256) void prior_kernel(
    const float* __restrict__ sigma, float* __restrict__ prior)
{
    const int tid = threadIdx.x;
    const int w = tid >> 6, tc = tid & 63;
    const int row = blockIdx.x * 4 + w;      // 0..32767
    const int t = row & 1023;

    float sg = sigma[row];
    float c = 1.f / (2.f * (sg*sg + 1e-6f));

    float e[16]; float sum = 0.f;
    #pragma unroll
    for (int j = 0; j < 16; ++j) {
        int s = j*64 + tc;
        float d = (float)(t - s);
        e[j] = __expf(-(d*d) * c);
        sum += e[j];
    }
    sum += __shfl_xor(sum, 32);
    sum += __shfl_xor(sum, 16);
    sum += __shfl_xor(sum, 8);
    sum += __shfl_xor(sum, 4);
    sum += __shfl_xor(sum, 2);
    sum += __shfl_xor(sum, 1);
    float inv = 1.f / (sum + 1e-9f);

    float* pr = prior + (size_t)row * 1024;
    #pragma unroll
    for (int j = 0; j < 16; ++j) pr[j*64 + tc] = e[j] * inv;
}

// ---------------------------------------------------------------------------
extern "C" void kernel_launch(void* const* d_in, const int* in_sizes, int n_in,
                              void* d_out, int out_size, void* d_ws, size_t ws_size,
                              hipStream_t stream)
{
    const float* x    = (const float*)d_in[0];
    const float* Wq_w = (const float*)d_in[1];
    const float* Wq_b = (const float*)d_in[2];
    const float* Wk_w = (const float*)d_in[3];
    const float* Wk_b = (const float*)d_in[4];
    const float* Wv_w = (const float*)d_in[5];
    const float* Wv_b = (const float*)d_in[6];
    const float* Ws_w = (const float*)d_in[7];
    const float* Ws_b = (const float*)d_in[8];
    const float* Wo_w = (const float*)d_in[9];
    const float* Wo_b = (const float*)d_in[10];

    float* out    = (float*)d_out;                      // [B,T,D]
    float* series = out + (size_t)BB*TT*DD;             // [B,H,T,T]
    float* prior  = series + (size_t)BB*HH*TT*TT;       // [B,H,T,T]
    float* sigma  = prior + (size_t)BB*HH*TT*TT;        // [B,H,T]

    const size_t nqkv = (size_t)BB*HH*TT*DHH;           // 2,097,152
    unsigned short* qbf = (unsigned short*)d_ws;
    unsigned short* kbf = qbf + nqkv;
    unsigned short* vbf = kbf + nqkv;
    float* oh = (float*)(vbf + nqkv);                   // [B,H,T,DH] f32

    proj_kernel<<<dim3(25, 64), 256, 0, stream>>>(
        x, Wq_w, Wq_b, Wk_w, Wk_b, Wv_w, Wv_b, Ws_w, Ws_b,
        qbf, kbf, vbf, sigma);

    attn_kernel<<<dim3(16, 32), 256, 0, stream>>>(qbf, kbf, vbf, series, oh);

    outproj_kernel<<<dim3(8, 64), 256, 0, stream>>>(oh, Wo_w, Wo_b, out);

    prior_kernel<<<8192, 256, 0, stream>>>(sigma, prior);
}

// Round 3
// 122.735 us; speedup vs baseline: 4.6466x; 1.9085x over previous
//
#include <hip/hip_runtime.h>
#include <math.h>

#define BB 4
#define TT 1024
#define DD 512
#define HH 8
#define DHH 64

typedef short bf8_t __attribute__((ext_vector_type(8)));
typedef float f32x4 __attribute__((ext_vector_type(4)));

__device__ __forceinline__ float softplus_f(float z) {
    return fmaxf(z, 0.f) + log1pf(__expf(-fabsf(z)));
}

__device__ __forceinline__ unsigned short f2bf(float f) {
    union { float f; unsigned int u; } v; v.f = f;
    return (unsigned short)((v.u + 0x7FFFu + ((v.u >> 16) & 1u)) >> 16);
}

// ---------------------------------------------------------------------------
// K0a: cast x (f32 [4096][512]) -> bf16
// ---------------------------------------------------------------------------
__global__ __launch_bounds__(256) void cast_x_kernel(
    const float* __restrict__ x, unsigned short* __restrict__ xbf)
{
    int i = blockIdx.x * 256 + threadIdx.x;   // 8 elems per thread
    float4 a = *(const float4*)&x[(size_t)i * 8];
    float4 b = *(const float4*)&x[(size_t)i * 8 + 4];
    union { unsigned short u[8]; int4 v; } o;
    o.u[0] = f2bf(a.x); o.u[1] = f2bf(a.y); o.u[2] = f2bf(a.z); o.u[3] = f2bf(a.w);
    o.u[4] = f2bf(b.x); o.u[5] = f2bf(b.y); o.u[6] = f2bf(b.z); o.u[7] = f2bf(b.w);
    *(int4*)&xbf[(size_t)i * 8] = o.v;
}

// ---------------------------------------------------------------------------
// K0b: transpose+cast the 512x512 weights into W^T bf16 [n][k].
// z: 0=Wq(rows 0..511 of wt) 1=Wk(512..) 2=Wv(1024..) 3=Wo(->woT)
// ---------------------------------------------------------------------------
__global__ __launch_bounds__(256) void transpose_w_kernel(
    const float* __restrict__ Wq, const float* __restrict__ Wk,
    const float* __restrict__ Wv, const float* __restrict__ Wo,
    unsigned short* __restrict__ wt, unsigned short* __restrict__ woT)
{
    __shared__ float tile[32][33];
    const int tid = threadIdx.x;
    const int z = blockIdx.z;
    const float* W = (z == 0) ? Wq : (z == 1) ? Wk : (z == 2) ? Wv : Wo;
    unsigned short* dst = (z < 3) ? (wt + (size_t)z * 512 * 512) : woT;
    const int k0 = blockIdx.x * 32, n0 = blockIdx.y * 32;
    const int ty = tid >> 3, tx = tid & 7;

    float4 v = *(const float4*)&W[(size_t)(k0 + ty) * 512 + n0 + tx * 4];
    tile[ty][tx*4+0] = v.x; tile[ty][tx*4+1] = v.y;
    tile[ty][tx*4+2] = v.z; tile[ty][tx*4+3] = v.w;
    __syncthreads();
    ushort4 o;
    o.x = f2bf(tile[tx*4+0][ty]);
    o.y = f2bf(tile[tx*4+1][ty]);
    o.z = f2bf(tile[tx*4+2][ty]);
    o.w = f2bf(tile[tx*4+3][ty]);
    *(ushort4*)&dst[(size_t)(n0 + ty) * 512 + k0 + tx * 4] = o;
}

// K0c: Ws [512][8] -> wt rows 1536..1543
__global__ __launch_bounds__(256) void transpose_ws_kernel(
    const float* __restrict__ Ws, unsigned short* __restrict__ wt)
{
    const int tid = threadIdx.x;
    #pragma unroll
    for (int i = 0; i < 16; ++i) {
        int idx = i * 256 + tid;          // = k*8 + n
        int k = idx >> 3, n = idx & 7;
        wt[(size_t)(1536 + n) * 512 + k] = f2bf(Ws[idx]);
    }
}

// ---------------------------------------------------------------------------
// K1: proj GEMM via MFMA: C[4096,1544] = xbf @ wt^T.
// Block = 64x64 tile, 4 waves (16 rows each). XOR-swizzled LDS tiles.
// Epilogue: q(x0.125)/k/v bf16 [B,H,T,64]; sigma (softplus+1e-6) f32.
// ---------------------------------------------------------------------------
__global__ __launch_bounds__(256) void proj_mfma_kernel(
    const unsigned short* __restrict__ xbf,   // [4096][512]
    const unsigned short* __restrict__ wt,    // [1600][512], rows 0..1543 valid
    const float* __restrict__ bq, const float* __restrict__ bk,
    const float* __restrict__ bv, const float* __restrict__ bs,
    unsigned short* __restrict__ qbf, unsigned short* __restrict__ kbf,
    unsigned short* __restrict__ vbf, float* __restrict__ sigma_out)
{
    __shared__ unsigned short a_s[64][64];
    __shared__ unsigned short b_s[64][64];
    const int tid = threadIdx.x;
    const int w = tid >> 6, l = tid & 63, lr = l & 15, lg = l >> 4;
    const int ct = blockIdx.x;          // 0..24
    const int m0 = blockIdx.y * 64;
    const int n0 = ct * 64;

    f32x4 acc[4];
    #pragma unroll
    for (int nb = 0; nb < 4; ++nb) acc[nb] = (f32x4){0.f, 0.f, 0.f, 0.f};

    for (int k0 = 0; k0 < 512; k0 += 64) {
        __syncthreads();
        #pragma unroll
        for (int rep = 0; rep < 2; ++rep) {
            int idx = rep * 256 + tid;
            int row = idx >> 3, cg = idx & 7;
            *(int4*)&a_s[row][(cg ^ (row & 7)) * 8] =
                *(const int4*)&xbf[(size_t)(m0 + row) * 512 + k0 + cg * 8];
            *(int4*)&b_s[row][(cg ^ (row & 7)) * 8] =
                *(const int4*)&wt[(size_t)(n0 + row) * 512 + k0 + cg * 8];
        }
        __syncthreads();
        #pragma unroll
        for (int ks = 0; ks < 2; ++ks) {
            int arow = w * 16 + lr;
            bf8_t af = *(const bf8_t*)&a_s[arow][((ks*4 + lg) ^ (arow & 7)) * 8];
            #pragma unroll
            for (int nb = 0; nb < 4; ++nb) {
                int brow = nb * 16 + lr;
                bf8_t bf = *(const bf8_t*)&b_s[brow][((ks*4 + lg) ^ (brow & 7)) * 8];
                acc[nb] = __builtin_amdgcn_mfma_f32_16x16x32_bf16(af, bf, acc[nb], 0, 0, 0);
            }
        }
    }

    if (ct < 24) {
        const int seg = ct >> 3;
        const int h = ct & 7;
        const float* bias = (seg == 0) ? bq : (seg == 1) ? bk : bv;
        unsigned short* dst = (seg == 0) ? qbf : (seg == 1) ? kbf : vbf;
        const float sc = (seg == 0) ? 0.125f : 1.f;
        #pragma unroll
        for (int nb = 0; nb < 4; ++nb) {
            float bb = bias[h * 64 + nb * 16 + lr];
            #pragma unroll
            for (int r = 0; r < 4; ++r) {
                int m = m0 + w * 16 + lg * 4 + r;
                int b = m >> 10, t = m & 1023;
                dst[((size_t)((b*HH + h)*TT + t)) * 64 + nb * 16 + lr] =
                    f2bf((acc[nb][r] + bb) * sc);
            }
        }
    } else if (lr < 8) {
        float bb = bs[lr];
        #pragma unroll
        for (int r = 0; r < 4; ++r) {
            int m = m0 + w * 16 + lg * 4 + r;
            int b = m >> 10, t = m & 1023;
            sigma_out[(size_t)(b*HH + lr)*TT + t] = softplus_f(acc[0][r] + bb) + 1e-6f;
        }
    }
}

// ---------------------------------------------------------------------------
// K2: fused attention: series = softmax(QK^T/8) (written), obf = series @ V
// (bf16, [b,t,h*64+dh] layout for the out-projection).
// ---------------------------------------------------------------------------
__global__ __launch_bounds__(256) void attn_kernel(
    const unsigned short* __restrict__ qbf,
    const unsigned short* __restrict__ kbf,
    const unsigned short* __restrict__ vbf,
    float* __restrict__ series, unsigned short* __restrict__ obf)
{
    __shared__ unsigned short k_lds[64][72];   // K chunk, row-major [s][dh]
    __shared__ unsigned short v_lds[64][64];   // V^T chunk [dh][s], swizzled
    __shared__ unsigned short p_lds[4][16][72];// per-wave P tile [qrow][s]

    const int tid = threadIdx.x;
    const int w  = tid >> 6, l = tid & 63;
    const int lr = l & 15,  lg = l >> 4;
    const int bh = blockIdx.y;
    const int qr = blockIdx.x * 64 + w * 16;

    bf8_t aq[2];
    {
        const unsigned short* qrow = &qbf[((size_t)bh * TT + qr + lr) * 64];
        aq[0] = *(const bf8_t*)&qrow[lg * 8];
        aq[1] = *(const bf8_t*)&qrow[32 + lg * 8];
    }

    // ---------------- sweep 1: row sums ----------------
    float psum[4] = {0.f, 0.f, 0.f, 0.f};
    for (int st = 0; st < 16; ++st) {
        __syncthreads();
        #pragma unroll
        for (int rep = 0; rep < 2; ++rep) {
            int idx = rep * 256 + tid;
            int tr = idx >> 3, cg = idx & 7;
            *(int4*)&k_lds[tr][cg * 8] =
                *(const int4*)&kbf[((size_t)bh * TT + st * 64 + tr) * 64 + cg * 8];
        }
        __syncthreads();
        #pragma unroll
        for (int nb = 0; nb < 4; ++nb) {
            f32x4 acc = {0.f, 0.f, 0.f, 0.f};
            #pragma unroll
            for (int c = 0; c < 2; ++c) {
                bf8_t bk = *(const bf8_t*)&k_lds[nb * 16 + lr][c * 32 + lg * 8];
                acc = __builtin_amdgcn_mfma_f32_16x16x32_bf16(aq[c], bk, acc, 0, 0, 0);
            }
            #pragma unroll
            for (int r = 0; r < 4; ++r) psum[r] += __expf(acc[r]);
        }
    }
    #pragma unroll
    for (int r = 0; r < 4; ++r) {
        psum[r] += __shfl_xor(psum[r], 1);
        psum[r] += __shfl_xor(psum[r], 2);
        psum[r] += __shfl_xor(psum[r], 4);
        psum[r] += __shfl_xor(psum[r], 8);
    }
    float inv[4];
    #pragma unroll
    for (int r = 0; r < 4; ++r) inv[r] = 1.f / psum[r];

    // ---------------- sweep 2: series + PV ----------------
    f32x4 oacc[4];
    #pragma unroll
    for (int nb = 0; nb < 4; ++nb) oacc[nb] = (f32x4){0.f, 0.f, 0.f, 0.f};

    for (int st = 0; st < 16; ++st) {
        __syncthreads();
        #pragma unroll
        for (int rep = 0; rep < 2; ++rep) {
            int idx = rep * 256 + tid;
            int tr = idx >> 3, cg = idx & 7;
            *(int4*)&k_lds[tr][cg * 8] =
                *(const int4*)&kbf[((size_t)bh * TT + st * 64 + tr) * 64 + cg * 8];
        }
        #pragma unroll
        for (int rep = 0; rep < 2; ++rep) {
            int idx = rep * 256 + tid;
            int sr = idx >> 3, cg = idx & 7;
            int4 vv = *(const int4*)&vbf[((size_t)bh * TT + st * 64 + sr) * 64 + cg * 8];
            const unsigned short* pv = (const unsigned short*)&vv;
            #pragma unroll
            for (int j = 0; j < 8; ++j) {
                int row = cg * 8 + j;
                int gsw = ((sr >> 3) ^ j ^ cg) & 7;
                v_lds[row][gsw * 8 + (sr & 7)] = pv[j];
            }
        }
        __syncthreads();

        #pragma unroll
        for (int nb = 0; nb < 4; ++nb) {
            f32x4 acc = {0.f, 0.f, 0.f, 0.f};
            #pragma unroll
            for (int c = 0; c < 2; ++c) {
                bf8_t bk = *(const bf8_t*)&k_lds[nb * 16 + lr][c * 32 + lg * 8];
                acc = __builtin_amdgcn_mfma_f32_16x16x32_bf16(aq[c], bk, acc, 0, 0, 0);
            }
            #pragma unroll
            for (int r = 0; r < 4; ++r) {
                float e = __expf(acc[r]);
                series[((size_t)bh * TT + qr + lg * 4 + r) * TT + st * 64 + nb * 16 + lr]
                    = e * inv[r];
                p_lds[w][lg * 4 + r][nb * 16 + lr] = f2bf(e);
            }
        }

        bf8_t pa0 = *(const bf8_t*)&p_lds[w][lr][lg * 8];
        bf8_t pa1 = *(const bf8_t*)&p_lds[w][lr][32 + lg * 8];
        #pragma unroll
        for (int nb = 0; nb < 4; ++nb) {
            #pragma unroll
            for (int c = 0; c < 2; ++c) {
                int row = nb * 16 + lr;
                int gsw = ((c * 4 + lg) ^ (row & 7) ^ (row >> 3)) & 7;
                bf8_t bv = *(const bf8_t*)&v_lds[row][gsw * 8];
                oacc[nb] = __builtin_amdgcn_mfma_f32_16x16x32_bf16(
                    (c == 0) ? pa0 : pa1, bv, oacc[nb], 0, 0, 0);
            }
        }
    }

    const int b = bh >> 3, h = bh & 7;
    #pragma unroll
    for (int nb = 0; nb < 4; ++nb)
        #pragma unroll
        for (int r = 0; r < 4; ++r) {
            int t = qr + lg * 4 + r;
            obf[((size_t)(b * TT + t)) * 512 + h * 64 + nb * 16 + lr] =
                f2bf(oacc[nb][r] * inv[r]);
        }
}

// ---------------------------------------------------------------------------
// K3: out = obf[4096,512] @ woT^T + bo (MFMA), f32 out.
// ---------------------------------------------------------------------------
__global__ __launch_bounds__(256) void outproj_mfma_kernel(
    const unsigned short* __restrict__ obf,   // [4096][512]
    const unsigned short* __restrict__ woT,   // [512][512]
    const float* __restrict__ bo, float* __restrict__ out)
{
    __shared__ unsigned short a_s[64][64];
    __shared__ unsigned short b_s[64][64];
    const int tid = threadIdx.x;
    const int w = tid >> 6, l = tid & 63, lr = l & 15, lg = l >> 4;
    const int n0 = blockIdx.x * 64;
    const int m0 = blockIdx.y * 64;

    f32x4 acc[4];
    #pragma unroll
    for (int nb = 0; nb < 4; ++nb) acc[nb] = (f32x4){0.f, 0.f, 0.f, 0.f};

    for (int k0 = 0; k0 < 512; k0 += 64) {
        __syncthreads();
        #pragma unroll
        for (int rep = 0; rep < 2; ++rep) {
            int idx = rep * 256 + tid;
            int row = idx >> 3, cg = idx & 7;
            *(int4*)&a_s[row][(cg ^ (row & 7)) * 8] =
                *(const int4*)&obf[(size_t)(m0 + row) * 512 + k0 + cg * 8];
            *(int4*)&b_s[row][(cg ^ (row & 7)) * 8] =
                *(const int4*)&woT[(size_t)(n0 + row) * 512 + k0 + cg * 8];
        }
        __syncthreads();
        #pragma unroll
        for (int ks = 0; ks < 2; ++ks) {
            int arow = w * 16 + lr;
            bf8_t af = *(const bf8_t*)&a_s[arow][((ks*4 + lg) ^ (arow & 7)) * 8];
            #pragma unroll
            for (int nb = 0; nb < 4; ++nb) {
                int brow = nb * 16 + lr;
                bf8_t bf = *(const bf8_t*)&b_s[brow][((ks*4 + lg) ^ (brow & 7)) * 8];
                acc[nb] = __builtin_amdgcn_mfma_f32_16x16x32_bf16(af, bf, acc[nb], 0, 0, 0);
            }
        }
    }

    #pragma unroll
    for (int nb = 0; nb < 4; ++nb) {
        float bb = bo[n0 + nb * 16 + lr];
        #pragma unroll
        for (int r = 0; r < 4; ++r) {
            int m = m0 + w * 16 + lg * 4 + r;
            out[(size_t)m * 512 + n0 + nb * 16 + lr] = acc[nb][r] + bb;
        }
    }
}

// ---------------------------------------------------------------------------
// K5: prior. One wave per (b,h,t) row.
// ---------------------------------------------------------------------------
__global__ __launch_bounds__(256) void prior_kernel(
    const float* __restrict__ sigma, float* __restrict__ prior)
{
    const int tid = threadIdx.x;
    const int w = tid >> 6, tc = tid & 63;
    const int row = blockIdx.x * 4 + w;
    const int t = row & 1023;

    float sg = sigma[row];
    float c = 1.f / (2.f * (sg*sg + 1e-6f));

    float e[16]; float sum = 0.f;
    #pragma unroll
    for (int j = 0; j < 16; ++j) {
        int s = j*64 + tc;
        float d = (float)(t - s);
        e[j] = __expf(-(d*d) * c);
        sum += e[j];
    }
    sum += __shfl_xor(sum, 32);
    sum += __shfl_xor(sum, 16);
    sum += __shfl_xor(sum, 8);
    sum += __shfl_xor(sum, 4);
    sum += __shfl_xor(sum, 2);
    sum += __shfl_xor(sum, 1);
    float inv = 1.f / (sum + 1e-9f);

    float* pr = prior + (size_t)row * 1024;
    #pragma unroll
    for (int j = 0; j < 16; ++j) pr[j*64 + tc] = e[j] * inv;
}

// ---------------------------------------------------------------------------
extern "C" void kernel_launch(void* const* d_in, const int* in_sizes, int n_in,
                              void* d_out, int out_size, void* d_ws, size_t ws_size,
                              hipStream_t stream)
{
    const float* x    = (const float*)d_in[0];
    const float* Wq_w = (const float*)d_in[1];
    const float* Wq_b = (const float*)d_in[2];
    const float* Wk_w = (const float*)d_in[3];
    const float* Wk_b = (const float*)d_in[4];
    const float* Wv_w = (const float*)d_in[5];
    const float* Wv_b = (const float*)d_in[6];
    const float* Ws_w = (const float*)d_in[7];
    const float* Ws_b = (const float*)d_in[8];
    const float* Wo_w = (const float*)d_in[9];
    const float* Wo_b = (const float*)d_in[10];

    float* out    = (float*)d_out;                      // [B,T,D]
    float* series = out + (size_t)BB*TT*DD;             // [B,H,T,T]
    float* prior  = series + (size_t)BB*HH*TT*TT;       // [B,H,T,T]
    float* sigma  = prior + (size_t)BB*HH*TT*TT;        // [B,H,T]

    const size_t nx = (size_t)BB*TT*DD;                 // 2,097,152
    unsigned short* xbf = (unsigned short*)d_ws;        // [4096][512]
    unsigned short* wt  = xbf + nx;                     // [1600][512]
    unsigned short* woT = wt + (size_t)1600*512;        // [512][512]
    unsigned short* qbf = woT + (size_t)512*512;        // [B,H,T,64]
    unsigned short* kbf = qbf + nx;
    unsigned short* vbf = kbf + nx;
    unsigned short* obf = vbf + nx;                     // [4096][512]

    cast_x_kernel<<<1024, 256, 0, stream>>>(x, xbf);
    transpose_w_kernel<<<dim3(16, 16, 4), 256, 0, stream>>>(
        Wq_w, Wk_w, Wv_w, Wo_w, wt, woT);
    transpose_ws_kernel<<<1, 256, 0, stream>>>(Ws_w, wt);

    proj_mfma_kernel<<<dim3(25, 64), 256, 0, stream>>>(
        xbf, wt, Wq_b, Wk_b, Wv_b, Ws_b, qbf, kbf, vbf, sigma);

    attn_kernel<<<dim3(16, 32), 256, 0, stream>>>(qbf, kbf, vbf, series, obf);

    outproj_mfma_kernel<<<dim3(8, 64), 256, 0, stream>>>(obf, woT, Wo_b, out);

    prior_kernel<<<8192, 256, 0, stream>>>(sigma, prior);
}

// Round 4
// 117.565 us; speedup vs baseline: 4.8510x; 1.0440x over previous
//
#include <hip/hip_runtime.h>
#include <math.h>

#define BB 4
#define TT 1024
#define DD 512
#define HH 8
#define DHH 64

typedef short bf8_t __attribute__((ext_vector_type(8)));
typedef float f32x4 __attribute__((ext_vector_type(4)));

__device__ __forceinline__ float softplus_f(float z) {
    return fmaxf(z, 0.f) + log1pf(__expf(-fabsf(z)));
}

__device__ __forceinline__ unsigned short f2bf(float f) {
    union { float f; unsigned int u; } v; v.f = f;
    return (unsigned short)((v.u + 0x7FFFu + ((v.u >> 16) & 1u)) >> 16);
}

// ---------------------------------------------------------------------------
// K0a: cast x (f32 [4096][512]) -> bf16
// ---------------------------------------------------------------------------
__global__ __launch_bounds__(256) void cast_x_kernel(
    const float* __restrict__ x, unsigned short* __restrict__ xbf)
{
    int i = blockIdx.x * 256 + threadIdx.x;   // 8 elems per thread
    float4 a = *(const float4*)&x[(size_t)i * 8];
    float4 b = *(const float4*)&x[(size_t)i * 8 + 4];
    union { unsigned short u[8]; int4 v; } o;
    o.u[0] = f2bf(a.x); o.u[1] = f2bf(a.y); o.u[2] = f2bf(a.z); o.u[3] = f2bf(a.w);
    o.u[4] = f2bf(b.x); o.u[5] = f2bf(b.y); o.u[6] = f2bf(b.z); o.u[7] = f2bf(b.w);
    *(int4*)&xbf[(size_t)i * 8] = o.v;
}

// ---------------------------------------------------------------------------
// K0b: transpose+cast the 512x512 weights into W^T bf16 [n][k].
// ---------------------------------------------------------------------------
__global__ __launch_bounds__(256) void transpose_w_kernel(
    const float* __restrict__ Wq, const float* __restrict__ Wk,
    const float* __restrict__ Wv, const float* __restrict__ Wo,
    unsigned short* __restrict__ wt, unsigned short* __restrict__ woT)
{
    __shared__ float tile[32][33];
    const int tid = threadIdx.x;
    const int z = blockIdx.z;
    const float* W = (z == 0) ? Wq : (z == 1) ? Wk : (z == 2) ? Wv : Wo;
    unsigned short* dst = (z < 3) ? (wt + (size_t)z * 512 * 512) : woT;
    const int k0 = blockIdx.x * 32, n0 = blockIdx.y * 32;
    const int ty = tid >> 3, tx = tid & 7;

    float4 v = *(const float4*)&W[(size_t)(k0 + ty) * 512 + n0 + tx * 4];
    tile[ty][tx*4+0] = v.x; tile[ty][tx*4+1] = v.y;
    tile[ty][tx*4+2] = v.z; tile[ty][tx*4+3] = v.w;
    __syncthreads();
    ushort4 o;
    o.x = f2bf(tile[tx*4+0][ty]);
    o.y = f2bf(tile[tx*4+1][ty]);
    o.z = f2bf(tile[tx*4+2][ty]);
    o.w = f2bf(tile[tx*4+3][ty]);
    *(ushort4*)&dst[(size_t)(n0 + ty) * 512 + k0 + tx * 4] = o;
}

// K0c: Ws [512][8] -> wt rows 1536..1543
__global__ __launch_bounds__(256) void transpose_ws_kernel(
    const float* __restrict__ Ws, unsigned short* __restrict__ wt)
{
    const int tid = threadIdx.x;
    #pragma unroll
    for (int i = 0; i < 16; ++i) {
        int idx = i * 256 + tid;          // = k*8 + n
        int k = idx >> 3, n = idx & 7;
        wt[(size_t)(1536 + n) * 512 + k] = f2bf(Ws[idx]);
    }
}

// ---------------------------------------------------------------------------
// K1: proj GEMM via MFMA: C[4096,1544] = xbf @ wt^T.
// ---------------------------------------------------------------------------
__global__ __launch_bounds__(256) void proj_mfma_kernel(
    const unsigned short* __restrict__ xbf,   // [4096][512]
    const unsigned short* __restrict__ wt,    // [1600][512], rows 0..1543 valid
    const float* __restrict__ bq, const float* __restrict__ bk,
    const float* __restrict__ bv, const float* __restrict__ bs,
    unsigned short* __restrict__ qbf, unsigned short* __restrict__ kbf,
    unsigned short* __restrict__ vbf, float* __restrict__ sigma_out)
{
    __shared__ unsigned short a_s[64][64];
    __shared__ unsigned short b_s[64][64];
    const int tid = threadIdx.x;
    const int w = tid >> 6, l = tid & 63, lr = l & 15, lg = l >> 4;
    const int ct = blockIdx.x;          // 0..24
    const int m0 = blockIdx.y * 64;
    const int n0 = ct * 64;

    f32x4 acc[4];
    #pragma unroll
    for (int nb = 0; nb < 4; ++nb) acc[nb] = (f32x4){0.f, 0.f, 0.f, 0.f};

    for (int k0 = 0; k0 < 512; k0 += 64) {
        __syncthreads();
        #pragma unroll
        for (int rep = 0; rep < 2; ++rep) {
            int idx = rep * 256 + tid;
            int row = idx >> 3, cg = idx & 7;
            *(int4*)&a_s[row][(cg ^ (row & 7)) * 8] =
                *(const int4*)&xbf[(size_t)(m0 + row) * 512 + k0 + cg * 8];
            *(int4*)&b_s[row][(cg ^ (row & 7)) * 8] =
                *(const int4*)&wt[(size_t)(n0 + row) * 512 + k0 + cg * 8];
        }
        __syncthreads();
        #pragma unroll
        for (int ks = 0; ks < 2; ++ks) {
            int arow = w * 16 + lr;
            bf8_t af = *(const bf8_t*)&a_s[arow][((ks*4 + lg) ^ (arow & 7)) * 8];
            #pragma unroll
            for (int nb = 0; nb < 4; ++nb) {
                int brow = nb * 16 + lr;
                bf8_t bf = *(const bf8_t*)&b_s[brow][((ks*4 + lg) ^ (brow & 7)) * 8];
                acc[nb] = __builtin_amdgcn_mfma_f32_16x16x32_bf16(af, bf, acc[nb], 0, 0, 0);
            }
        }
    }

    if (ct < 24) {
        const int seg = ct >> 3;
        const int h = ct & 7;
        const float* bias = (seg == 0) ? bq : (seg == 1) ? bk : bv;
        unsigned short* dst = (seg == 0) ? qbf : (seg == 1) ? kbf : vbf;
        const float sc = (seg == 0) ? 0.125f : 1.f;
        #pragma unroll
        for (int nb = 0; nb < 4; ++nb) {
            float bb = bias[h * 64 + nb * 16 + lr];
            #pragma unroll
            for (int r = 0; r < 4; ++r) {
                int m = m0 + w * 16 + lg * 4 + r;
                int b = m >> 10, t = m & 1023;
                dst[((size_t)((b*HH + h)*TT + t)) * 64 + nb * 16 + lr] =
                    f2bf((acc[nb][r] + bb) * sc);
            }
        }
    } else if (lr < 8) {
        float bb = bs[lr];
        #pragma unroll
        for (int r = 0; r < 4; ++r) {
            int m = m0 + w * 16 + lg * 4 + r;
            int b = m >> 10, t = m & 1023;
            sigma_out[(size_t)(b*HH + lr)*TT + t] = softplus_f(acc[0][r] + bb) + 1e-6f;
        }
    }
}

// ---------------------------------------------------------------------------
// K2: fused attention + prior:
//   series = softmax(QK^T/8), obf = series @ V (bf16, [b,t,h*64+dh]),
//   prior rows for this block's (bh, q-rows) interleaved into sweep 2
//   (prior is VALU/store work that hides under MFMA shadow).
// ---------------------------------------------------------------------------
__global__ __launch_bounds__(256) void attn_kernel(
    const unsigned short* __restrict__ qbf,
    const unsigned short* __restrict__ kbf,
    const unsigned short* __restrict__ vbf,
    const float* __restrict__ sigma,
    float* __restrict__ series, float* __restrict__ prior,
    unsigned short* __restrict__ obf)
{
    __shared__ unsigned short k_lds[64][72];   // K chunk, row-major [s][dh]
    __shared__ unsigned short v_lds[64][64];   // V^T chunk [dh][s], swizzled
    __shared__ unsigned short p_lds[4][16][72];// per-wave P tile [qrow][s]

    const int tid = threadIdx.x;
    const int w  = tid >> 6, l = tid & 63;
    const int lr = l & 15,  lg = l >> 4;
    const int bh = blockIdx.y;
    const int qr = blockIdx.x * 64 + w * 16;

    bf8_t aq[2];
    {
        const unsigned short* qrow = &qbf[((size_t)bh * TT + qr + lr) * 64];
        aq[0] = *(const bf8_t*)&qrow[lg * 8];
        aq[1] = *(const bf8_t*)&qrow[32 + lg * 8];
    }

    // ---------------- sweep 1: row sums ----------------
    float psum[4] = {0.f, 0.f, 0.f, 0.f};
    for (int st = 0; st < 16; ++st) {
        __syncthreads();
        #pragma unroll
        for (int rep = 0; rep < 2; ++rep) {
            int idx = rep * 256 + tid;
            int tr = idx >> 3, cg = idx & 7;
            *(int4*)&k_lds[tr][cg * 8] =
                *(const int4*)&kbf[((size_t)bh * TT + st * 64 + tr) * 64 + cg * 8];
        }
        __syncthreads();
        #pragma unroll
        for (int nb = 0; nb < 4; ++nb) {
            f32x4 acc = {0.f, 0.f, 0.f, 0.f};
            #pragma unroll
            for (int c = 0; c < 2; ++c) {
                bf8_t bk = *(const bf8_t*)&k_lds[nb * 16 + lr][c * 32 + lg * 8];
                acc = __builtin_amdgcn_mfma_f32_16x16x32_bf16(aq[c], bk, acc, 0, 0, 0);
            }
            #pragma unroll
            for (int r = 0; r < 4; ++r) psum[r] += __expf(acc[r]);
        }
    }
    #pragma unroll
    for (int r = 0; r < 4; ++r) {
        psum[r] += __shfl_xor(psum[r], 1);
        psum[r] += __shfl_xor(psum[r], 2);
        psum[r] += __shfl_xor(psum[r], 4);
        psum[r] += __shfl_xor(psum[r], 8);
    }
    float inv[4];
    #pragma unroll
    for (int r = 0; r < 4; ++r) inv[r] = 1.f / psum[r];

    // ---------------- sweep 2: series + PV + prior ----------------
    f32x4 oacc[4];
    #pragma unroll
    for (int nb = 0; nb < 4; ++nb) oacc[nb] = (f32x4){0.f, 0.f, 0.f, 0.f};

    for (int st = 0; st < 16; ++st) {
        __syncthreads();
        #pragma unroll
        for (int rep = 0; rep < 2; ++rep) {
            int idx = rep * 256 + tid;
            int tr = idx >> 3, cg = idx & 7;
            *(int4*)&k_lds[tr][cg * 8] =
                *(const int4*)&kbf[((size_t)bh * TT + st * 64 + tr) * 64 + cg * 8];
        }
        #pragma unroll
        for (int rep = 0; rep < 2; ++rep) {
            int idx = rep * 256 + tid;
            int sr = idx >> 3, cg = idx & 7;
            int4 vv = *(const int4*)&vbf[((size_t)bh * TT + st * 64 + sr) * 64 + cg * 8];
            const unsigned short* pv = (const unsigned short*)&vv;
            #pragma unroll
            for (int j = 0; j < 8; ++j) {
                int row = cg * 8 + j;
                int gsw = ((sr >> 3) ^ j ^ cg) & 7;
                v_lds[row][gsw * 8 + (sr & 7)] = pv[j];
            }
        }
        __syncthreads();

        #pragma unroll
        for (int nb = 0; nb < 4; ++nb) {
            f32x4 acc = {0.f, 0.f, 0.f, 0.f};
            #pragma unroll
            for (int c = 0; c < 2; ++c) {
                bf8_t bk = *(const bf8_t*)&k_lds[nb * 16 + lr][c * 32 + lg * 8];
                acc = __builtin_amdgcn_mfma_f32_16x16x32_bf16(aq[c], bk, acc, 0, 0, 0);
            }
            #pragma unroll
            for (int r = 0; r < 4; ++r) {
                float e = __expf(acc[r]);
                series[((size_t)bh * TT + qr + lg * 4 + r) * TT + st * 64 + nb * 16 + lr]
                    = e * inv[r];
                p_lds[w][lg * 4 + r][nb * 16 + lr] = f2bf(e);
            }
        }

        bf8_t pa0 = *(const bf8_t*)&p_lds[w][lr][lg * 8];
        bf8_t pa1 = *(const bf8_t*)&p_lds[w][lr][32 + lg * 8];
        #pragma unroll
        for (int nb = 0; nb < 4; ++nb) {
            #pragma unroll
            for (int c = 0; c < 2; ++c) {
                int row = nb * 16 + lr;
                int gsw = ((c * 4 + lg) ^ (row & 7) ^ (row >> 3)) & 7;
                bf8_t bv = *(const bf8_t*)&v_lds[row][gsw * 8];
                oacc[nb] = __builtin_amdgcn_mfma_f32_16x16x32_bf16(
                    (c == 0) ? pa0 : pa1, bv, oacc[nb], 0, 0, 0);
            }
        }

        // ---- prior row t = qr + st (VALU/TRANS/store; overlaps MFMA) ----
        {
            int t = qr + st;
            float sg = sigma[(size_t)bh * TT + t];
            float cc = 1.f / (2.f * (sg * sg + 1e-6f));
            float e[16]; float sum = 0.f;
            #pragma unroll
            for (int j = 0; j < 16; ++j) {
                float d = (float)(t - (j * 64 + l));
                e[j] = __expf(-(d * d) * cc);
                sum += e[j];
            }
            sum += __shfl_xor(sum, 32);
            sum += __shfl_xor(sum, 16);
            sum += __shfl_xor(sum, 8);
            sum += __shfl_xor(sum, 4);
            sum += __shfl_xor(sum, 2);
            sum += __shfl_xor(sum, 1);
            float pinv = 1.f / (sum + 1e-9f);
            float* pr = prior + ((size_t)bh * TT + t) * TT;
            #pragma unroll
            for (int j = 0; j < 16; ++j) pr[j * 64 + l] = e[j] * pinv;
        }
    }

    const int b = bh >> 3, h = bh & 7;
    #pragma unroll
    for (int nb = 0; nb < 4; ++nb)
        #pragma unroll
        for (int r = 0; r < 4; ++r) {
            int t = qr + lg * 4 + r;
            obf[((size_t)(b * TT + t)) * 512 + h * 64 + nb * 16 + lr] =
                f2bf(oacc[nb][r] * inv[r]);
        }
}

// ---------------------------------------------------------------------------
// K3: out = obf[4096,512] @ woT^T + bo (MFMA), f32 out.
// ---------------------------------------------------------------------------
__global__ __launch_bounds__(256) void outproj_mfma_kernel(
    const unsigned short* __restrict__ obf,   // [4096][512]
    const unsigned short* __restrict__ woT,   // [512][512]
    const float* __restrict__ bo, float* __restrict__ out)
{
    __shared__ unsigned short a_s[64][64];
    __shared__ unsigned short b_s[64][64];
    const int tid = threadIdx.x;
    const int w = tid >> 6, l = tid & 63, lr = l & 15, lg = l >> 4;
    const int n0 = blockIdx.x * 64;
    const int m0 = blockIdx.y * 64;

    f32x4 acc[4];
    #pragma unroll
    for (int nb = 0; nb < 4; ++nb) acc[nb] = (f32x4){0.f, 0.f, 0.f, 0.f};

    for (int k0 = 0; k0 < 512; k0 += 64) {
        __syncthreads();
        #pragma unroll
        for (int rep = 0; rep < 2; ++rep) {
            int idx = rep * 256 + tid;
            int row = idx >> 3, cg = idx & 7;
            *(int4*)&a_s[row][(cg ^ (row & 7)) * 8] =
                *(const int4*)&obf[(size_t)(m0 + row) * 512 + k0 + cg * 8];
            *(int4*)&b_s[row][(cg ^ (row & 7)) * 8] =
                *(const int4*)&woT[(size_t)(n0 + row) * 512 + k0 + cg * 8];
        }
        __syncthreads();
        #pragma unroll
        for (int ks = 0; ks < 2; ++ks) {
            int arow = w * 16 + lr;
            bf8_t af = *(const bf8_t*)&a_s[arow][((ks*4 + lg) ^ (arow & 7)) * 8];
            #pragma unroll
            for (int nb = 0; nb < 4; ++nb) {
                int brow = nb * 16 + lr;
                bf8_t bf = *(const bf8_t*)&b_s[brow][((ks*4 + lg) ^ (brow & 7)) * 8];
                acc[nb] = __builtin_amdgcn_mfma_f32_16x16x32_bf16(af, bf, acc[nb], 0, 0, 0);
            }
        }
    }

    #pragma unroll
    for (int nb = 0; nb < 4; ++nb) {
        float bb = bo[n0 + nb * 16 + lr];
        #pragma unroll
        for (int r = 0; r < 4; ++r) {
            int m = m0 + w * 16 + lg * 4 + r;
            out[(size_t)m * 512 + n0 + nb * 16 + lr] = acc[nb][r] + bb;
        }
    }
}

// ---------------------------------------------------------------------------
extern "C" void kernel_launch(void* const* d_in, const int* in_sizes, int n_in,
                              void* d_out, int out_size, void* d_ws, size_t ws_size,
                              hipStream_t stream)
{
    const float* x    = (const float*)d_in[0];
    const float* Wq_w = (const float*)d_in[1];
    const float* Wq_b = (const float*)d_in[2];
    const float* Wk_w = (const float*)d_in[3];
    const float* Wk_b = (const float*)d_in[4];
    const float* Wv_w = (const float*)d_in[5];
    const float* Wv_b = (const float*)d_in[6];
    const float* Ws_w = (const float*)d_in[7];
    const float* Ws_b = (const float*)d_in[8];
    const float* Wo_w = (const float*)d_in[9];
    const float* Wo_b = (const float*)d_in[10];

    float* out    = (float*)d_out;                      // [B,T,D]
    float* series = out + (size_t)BB*TT*DD;             // [B,H,T,T]
    float* prior  = series + (size_t)BB*HH*TT*TT;       // [B,H,T,T]
    float* sigma  = prior + (size_t)BB*HH*TT*TT;        // [B,H,T]

    const size_t nx = (size_t)BB*TT*DD;                 // 2,097,152
    unsigned short* xbf = (unsigned short*)d_ws;        // [4096][512]
    unsigned short* wt  = xbf + nx;                     // [1600][512]
    unsigned short* woT = wt + (size_t)1600*512;        // [512][512]
    unsigned short* qbf = woT + (size_t)512*512;        // [B,H,T,64]
    unsigned short* kbf = qbf + nx;
    unsigned short* vbf = kbf + nx;
    unsigned short* obf = vbf + nx;                     // [4096][512]

    cast_x_kernel<<<1024, 256, 0, stream>>>(x, xbf);
    transpose_w_kernel<<<dim3(16, 16, 4), 256, 0, stream>>>(
        Wq_w, Wk_w, Wv_w, Wo_w, wt, woT);
    transpose_ws_kernel<<<1, 256, 0, stream>>>(Ws_w, wt);

    proj_mfma_kernel<<<dim3(25, 64), 256, 0, stream>>>(
        xbf, wt, Wq_b, Wk_b, Wv_b, Ws_b, qbf, kbf, vbf, sigma);

    attn_kernel<<<dim3(16, 32), 256, 0, stream>>>(
        qbf, kbf, vbf, sigma, series, prior, obf);

    outproj_mfma_kernel<<<dim3(8, 64), 256, 0, stream>>>(obf, woT, Wo_b, out);
}